// Round 1
// 1725.988 us; speedup vs baseline: 4.9362x; 4.9362x over previous
//
#include <hip/hip_runtime.h>

// Fixed shapes
#define B_    64
#define V_    16384
#define E_    524288
#define KCH   6
#define FCH   32
#define FIN1  65536
#define FC1F  512
#define FC2F  512
#define NN1F  1024
#define NN2F  512
#define OUTC  10
#define KT    128

// workspace layout (bytes), total 16,122,368
#define OFF_XS      0u           // bf16 xs[6][V][B]      12,582,912
#define OFF_SCOL    12582912u    // u16  scol[E]           1,048,576
#define OFF_SVAL    13631488u    // bf16 sval[E]           1,048,576
#define OFF_RSTART  14680064u    // i32  rstart[V+1]          66,048
#define OFF_CNT     14746112u    // i32  cnt/cursor[V]        65,536
#define OFF_CF      14811648u    // f32  Cf[64*1024]         262,144
#define OFF_SLICE   15073792u    // bf16 slice[64*8192]    1,048,576 (dead after fc1)
#define OFF_XD      15073792u    // f32  xd[64*512]   (overlays slice)
#define OFF_XN1     15204864u    // f32  xn1[64*1024] (overlays slice)
#define OFF_XN2     15467008u    // f32  xn2[64*512]  (overlays slice)

typedef __attribute__((ext_vector_type(4))) float v4f;

__device__ __forceinline__ float b2f(unsigned short h) {
    union { unsigned int u; float f; } v; v.u = ((unsigned int)h) << 16; return v.f;
}
__device__ __forceinline__ unsigned short f2b(float f) {
    union { float f; unsigned int u; } v; v.f = f;
    unsigned int u = v.u;
    u += 0x7fffu + ((u >> 16) & 1u);
    return (unsigned short)(u >> 16);
}

__global__ void prep_k(const float* __restrict__ xin, unsigned short* __restrict__ x0) {
    __shared__ unsigned short tl[64][65];
    int t = threadIdx.x;
    int v0 = blockIdx.x * 64;
    #pragma unroll
    for (int i = 0; i < 16; i++) {
        int idx = t + i * 256;
        int b = idx >> 6, v = idx & 63;
        tl[v][b] = f2b(xin[(size_t)b * V_ + v0 + v]);
    }
    __syncthreads();
    #pragma unroll
    for (int i = 0; i < 16; i++) {
        int idx = t + i * 256;
        int v = idx >> 6, b = idx & 63;
        x0[(size_t)(v0 + v) * B_ + b] = tl[v][b];
    }
}

__global__ void count_k(const int* __restrict__ rows, int* __restrict__ cnt) {
    int e = blockIdx.x * 256 + threadIdx.x;
    if (e < E_) atomicAdd(&cnt[rows[e] & (V_ - 1)], 1);
}

__global__ void scan_k(int* __restrict__ cnt_cursor, int* __restrict__ row_start) {
    __shared__ int sums[256];
    int t = threadIdx.x;
    int loc[64];
    int s = 0;
    #pragma unroll
    for (int i = 0; i < 64; i++) { loc[i] = cnt_cursor[t * 64 + i]; s += loc[i]; }
    sums[t] = s;
    __syncthreads();
    for (int off = 1; off < 256; off <<= 1) {
        int v = (t >= off) ? sums[t - off] : 0;
        __syncthreads();
        sums[t] += v;
        __syncthreads();
    }
    int base = (t == 0) ? 0 : sums[t - 1];
    #pragma unroll
    for (int i = 0; i < 64; i++) {
        row_start[t * 64 + i] = base;
        cnt_cursor[t * 64 + i] = base;
        base += loc[i];
    }
    if (t == 255) row_start[V_] = base;
}

__global__ void scatter_k(const int* __restrict__ rows, const int* __restrict__ cols,
                          const float* __restrict__ vals,
                          int* __restrict__ cursor, unsigned short* __restrict__ scol,
                          unsigned short* __restrict__ sval) {
    int e = blockIdx.x * 256 + threadIdx.x;
    if (e < E_) {
        int r = rows[e] & (V_ - 1);
        int p = atomicAdd(&cursor[r], 1);
        scol[p] = (unsigned short)(cols[e] & (V_ - 1));
        sval[p] = f2b(vals[e]);
    }
}

__global__ void spmm_k(const int* __restrict__ row_start, const unsigned short* __restrict__ scol,
                       const unsigned short* __restrict__ sval,
                       const unsigned short* __restrict__ x,
                       const unsigned short* __restrict__ xprev, unsigned short* __restrict__ y,
                       int mode) {
    int row  = blockIdx.x * 4 + (threadIdx.x >> 6);
    int lane = threadIdx.x & 63;
    int s = row_start[row], e = row_start[row + 1];
    float acc = 0.f;
    for (int i = s; i < e; i++)
        acc += b2f(sval[i]) * b2f(x[(size_t)scol[i] * B_ + lane]);
    size_t o = (size_t)row * B_ + lane;
    float r = mode ? (2.f * acc - b2f(xprev[o])) : acc;
    y[o] = f2b(r);
}

__global__ void cheby_slice_k(const unsigned short* __restrict__ xs, const float* __restrict__ w,
                              const float* __restrict__ bias, unsigned short* __restrict__ slice,
                              int g) {
    __shared__ float tile[KCH * 512];
    __shared__ float wf[FCH * KCH];
    __shared__ float bf[FCH];
    int t = threadIdx.x;
    int vpl = blockIdx.x;
    int vp = g * 256 + vpl;
    for (int i = t; i < KCH * 512; i += 256) {
        int k = i >> 9, rem = i & 511;
        tile[i] = b2f(xs[(size_t)k * V_ * B_ + (size_t)vp * 512 + rem]);
    }
    if (t < FCH * KCH) wf[t] = w[t];
    if (t < FCH) bf[t] = bias[t];
    __syncthreads();
    int f = t & 31, b0 = t >> 5;
    float wr[KCH];
    #pragma unroll
    for (int k = 0; k < KCH; k++) wr[k] = wf[f * KCH + k];
    float bb = bf[f];
    #pragma unroll
    for (int bi = 0; bi < 8; bi++) {
        int b = b0 * 8 + bi;
        float m = -1e30f;
        #pragma unroll
        for (int j = 0; j < 8; j++) {
            float s = bb;
            #pragma unroll
            for (int k = 0; k < KCH; k++) s += tile[k * 512 + j * 64 + b] * wr[k];
            m = fmaxf(m, s);
        }
        slice[(size_t)b * 8192 + vpl * FCH + f] = f2b(fmaxf(m, 0.f));
    }
}

// ---- generic VALU GEMM: C[64,N] (+)= A[64,*] @ W[N,*]^T ----
// direct=1: Co[m*N+n] = acc + bias[n] (relu?) f32 ; direct=0: atomicAdd(Cf).
__global__ void gemm_k(const void* __restrict__ Av, int a32, int lda, int ka0,
                       const float* __restrict__ W, int ldw, int kw0,
                       int klen, int N, const float* __restrict__ bias,
                       int relu, int direct,
                       float* __restrict__ Cf, float* __restrict__ Co) {
    __shared__ float As[64 * (KT + 1)];
    const unsigned short* Au = (const unsigned short*)Av;
    const float* Af = (const float*)Av;
    int t = threadIdx.x;
    int m = t & 63, ng = t >> 6;
    int nb = blockIdx.x * 16 + ng * 4;
    int ka = ka0 + blockIdx.y * klen;
    int kw = kw0 + blockIdx.y * klen;
    float acc0 = 0.f, acc1 = 0.f, acc2 = 0.f, acc3 = 0.f;
    for (int kt = 0; kt < klen; kt += KT) {
        __syncthreads();
        for (int idx = t; idx < 64 * KT; idx += 256) {
            int mm = idx >> 7, kk = idx & (KT - 1);
            size_t src = (size_t)mm * lda + ka + kt + kk;
            As[mm * (KT + 1) + kk] = a32 ? Af[src] : b2f(Au[src]);
        }
        __syncthreads();
        const float* W0 = W + (size_t)(nb + 0) * ldw + kw + kt;
        const float* W1 = W + (size_t)(nb + 1) * ldw + kw + kt;
        const float* W2 = W + (size_t)(nb + 2) * ldw + kw + kt;
        const float* W3 = W + (size_t)(nb + 3) * ldw + kw + kt;
        const float* Am = As + m * (KT + 1);
        for (int k = 0; k < KT; k += 4) {
            v4f w0 = *(const v4f*)(W0 + k);
            v4f w1 = *(const v4f*)(W1 + k);
            v4f w2 = *(const v4f*)(W2 + k);
            v4f w3 = *(const v4f*)(W3 + k);
            #pragma unroll
            for (int j = 0; j < 4; j++) {
                float av = Am[k + j];
                acc0 += av * w0[j];
                acc1 += av * w1[j];
                acc2 += av * w2[j];
                acc3 += av * w3[j];
            }
        }
    }
    float a4[4] = {acc0, acc1, acc2, acc3};
    #pragma unroll
    for (int j = 0; j < 4; j++) {
        int n = nb + j;
        if (direct) {
            float v = a4[j] + bias[n];
            if (relu) v = fmaxf(v, 0.f);
            Co[(size_t)m * N + n] = v;
        } else {
            atomicAdd(&Cf[(size_t)m * N + n], a4[j]);
        }
    }
}

__global__ void initbias_k(float* __restrict__ C, const float* __restrict__ bias, int nmask) {
    int i = blockIdx.x * 256 + threadIdx.x;
    C[i] = bias[i & nmask];
}

// f32 out with optional relu
__global__ void finish_k(const float* __restrict__ C, float* __restrict__ o, int relu) {
    int i = blockIdx.x * 256 + threadIdx.x;
    float v = C[i];
    if (relu) v = fmaxf(v, 0.f);
    o[i] = v;
}

__global__ void sum2_k(const float* __restrict__ xh, const float* __restrict__ xn,
                       const float* __restrict__ w, const float* __restrict__ bias,
                       float* __restrict__ out) {
    int b = blockIdx.x;
    int lane = threadIdx.x;
    float xc[16];
    #pragma unroll
    for (int j = 0; j < 8; j++) xc[j] = xh[b * FC1F + j * 64 + lane];
    #pragma unroll
    for (int j = 0; j < 8; j++) xc[8 + j] = xn[b * NN2F + j * 64 + lane];
    float logits[OUTC];
    #pragma unroll
    for (int o = 0; o < OUTC; o++) {
        float s = 0.f;
        #pragma unroll
        for (int j = 0; j < 16; j++) s += xc[j] * w[o * 1024 + j * 64 + lane];
        #pragma unroll
        for (int off = 32; off; off >>= 1) s += __shfl_xor(s, off);
        logits[o] = s + bias[o];
    }
    float mx = logits[0];
    #pragma unroll
    for (int o = 1; o < OUTC; o++) mx = fmaxf(mx, logits[o]);
    float lse = 0.f;
    #pragma unroll
    for (int o = 0; o < OUTC; o++) lse += expf(logits[o] - mx);
    float lg = logf(lse) + mx;
    if (lane < OUTC) out[b * OUTC + lane] = logits[lane] - lg;
}

extern "C" void kernel_launch(void* const* d_in, const int* in_sizes, int n_in,
                              void* d_out, int out_size, void* d_ws, size_t ws_size,
                              hipStream_t stream) {
    const float* x_in   = (const float*)d_in[0];
    const float* L_vals = (const float*)d_in[1];
    const float* cl1_w  = (const float*)d_in[2];
    const float* cl1_b  = (const float*)d_in[3];
    const float* fc1_w  = (const float*)d_in[4];
    const float* fc1_b  = (const float*)d_in[5];
    const float* fc2_w  = (const float*)d_in[6];
    const float* fc2_b  = (const float*)d_in[7];
    const float* fc3_w  = (const float*)d_in[8];
    const float* fc3_b  = (const float*)d_in[9];
    const float* nn1_w  = (const float*)d_in[10];
    const float* nn1_b  = (const float*)d_in[11];
    const float* nn2_w  = (const float*)d_in[12];
    const float* nn2_b  = (const float*)d_in[13];
    const float* sum2_w = (const float*)d_in[14];
    const float* sum2_b = (const float*)d_in[15];
    const int* L_rows = (const int*)d_in[16];
    const int* L_cols = (const int*)d_in[17];
    float* out = (float*)d_out;
    char* ws = (char*)d_ws;

    unsigned short* xs     = (unsigned short*)(ws + OFF_XS);
    unsigned short* scol   = (unsigned short*)(ws + OFF_SCOL);
    unsigned short* sval   = (unsigned short*)(ws + OFF_SVAL);
    int*            rstart = (int*)(ws + OFF_RSTART);
    int*            cnt    = (int*)(ws + OFF_CNT);
    float*          Cf     = (float*)(ws + OFF_CF);
    unsigned short* slice  = (unsigned short*)(ws + OFF_SLICE);
    float*          xd     = (float*)(ws + OFF_XD);
    float*          xn1    = (float*)(ws + OFF_XN1);
    float*          xn2    = (float*)(ws + OFF_XN2);

    float* out_decode = out;                          // f32 [64,16384]
    float* out_hidden = out + (size_t)B_ * V_;        // f32 [64,512]
    float* out_logp   = out_hidden + B_ * FC1F;       // f32 [64,10]

    prep_k<<<V_ / 64, 256, 0, stream>>>(x_in, xs);

    hipMemsetAsync(cnt, 0, V_ * sizeof(int), stream);
    count_k<<<E_ / 256, 256, 0, stream>>>(L_rows, cnt);
    scan_k<<<1, 256, 0, stream>>>(cnt, rstart);
    scatter_k<<<E_ / 256, 256, 0, stream>>>(L_rows, L_cols, L_vals, cnt, scol, sval);

    size_t VB = (size_t)V_ * B_;
    spmm_k<<<V_ / 4, 256, 0, stream>>>(rstart, scol, sval, xs, nullptr, xs + VB, 0);
    for (int k = 2; k < KCH; k++)
        spmm_k<<<V_ / 4, 256, 0, stream>>>(rstart, scol, sval,
                                           xs + (k - 1) * VB, xs + (k - 2) * VB, xs + k * VB, 1);

    // fc1 via 8 interleaved (cheby slice -> partial GEMM with K-split), finish -> out_hidden
    // K-split y=16 (klen=512): 32*16 = 512 blocks (2/CU) instead of 32 (0.125/CU).
    initbias_k<<<B_ * FC1F / 256, 256, 0, stream>>>(Cf, fc1_b, FC1F - 1);
    for (int g = 0; g < 8; g++) {
        cheby_slice_k<<<256, 256, 0, stream>>>(xs, cl1_w, cl1_b, slice, g);
        gemm_k<<<dim3(FC1F / 16, 16), 256, 0, stream>>>(slice, 0, 8192, 0,
                                                        fc1_w, FIN1, g * 8192,
                                                        512, FC1F, nullptr, 0, 0, Cf, nullptr);
    }
    finish_k<<<B_ * FC1F / 256, 256, 0, stream>>>(Cf, out_hidden, 1);

    // fc2 (K=512, split y=4, relu via finish) -> xd (f32)
    initbias_k<<<B_ * FC2F / 256, 256, 0, stream>>>(Cf, fc2_b, FC2F - 1);
    gemm_k<<<dim3(FC2F / 16, 4), 256, 0, stream>>>(out_hidden, 1, FC1F, 0,
                                                   fc2_w, FC1F, 0,
                                                   FC1F / 4, FC2F, nullptr, 0, 0, Cf, nullptr);
    finish_k<<<B_ * FC2F / 256, 256, 0, stream>>>(Cf, xd, 1);

    // fc3 (K=512, direct, no relu) -> x_decode (f32); 1024 blocks already
    gemm_k<<<dim3(V_ / 16, 1), 256, 0, stream>>>(xd, 1, FC2F, 0,
                                                 fc3_w, FC2F, 0,
                                                 FC2F, V_, fc3_b, 0, 1, nullptr, out_decode);

    // nn1 (K=16384, ksplit=16, relu) -> xn1 (f32): 64*16 = 1024 blocks
    initbias_k<<<B_ * NN1F / 256, 256, 0, stream>>>(Cf, nn1_b, NN1F - 1);
    gemm_k<<<dim3(NN1F / 16, 16), 256, 0, stream>>>(x_in, 1, V_, 0,
                                                    nn1_w, V_, 0,
                                                    V_ / 16, NN1F, nullptr, 0, 0, Cf, nullptr);
    finish_k<<<B_ * NN1F / 256, 256, 0, stream>>>(Cf, xn1, 1);

    // nn2 (K=1024, split y=4, relu via finish) -> xn2 (f32)
    initbias_k<<<B_ * NN2F / 256, 256, 0, stream>>>(Cf, nn2_b, NN2F - 1);
    gemm_k<<<dim3(NN2F / 16, 4), 256, 0, stream>>>(xn1, 1, NN1F, 0,
                                                   nn2_w, NN1F, 0,
                                                   NN1F / 4, NN2F, nullptr, 0, 0, Cf, nullptr);
    finish_k<<<B_ * NN2F / 256, 256, 0, stream>>>(Cf, xn2, 1);

    sum2_k<<<B_, 64, 0, stream>>>(out_hidden, xn2, sum2_w, sum2_b, out_logp);
}

// Round 3
// 1090.312 us; speedup vs baseline: 7.8142x; 1.5830x over previous
//
#include <hip/hip_runtime.h>

// Fixed shapes
#define B_    64
#define V_    16384
#define E_    524288
#define KCH   6
#define FCH   32
#define FIN1  65536
#define FC1F  512
#define FC2F  512
#define NN1F  1024
#define NN2F  512
#define OUTC  10
#define KT2   64

// workspace layout (bytes), total 16,122,368
#define OFF_XS      0u           // bf16 xs[6][V][B]      12,582,912 ; dead after last cheby_slice -> Cp for nn1/nn2
#define OFF_SCOL    12582912u    // u16  scol[E]           1,048,576 ; scol+sval dead after spmm -> Cp for fc1/fc2 (2 MB)
#define OFF_SVAL    13631488u    // bf16 sval[E]           1,048,576
#define OFF_RSTART  14680064u    // i32  rstart[V+1]          66,048
#define OFF_CNT     14746112u    // i32  cnt/cursor[V]        65,536
#define OFF_CF      14811648u    // f32  Cf[64*1024]         262,144 (unused now)
#define OFF_SLICE   15073792u    // bf16 slice[64*8192]    1,048,576 (dead after fc1)
#define OFF_XD      15073792u    // f32  xd[64*512]   (overlays slice)
#define OFF_XN1     15204864u    // f32  xn1[64*1024] (overlays slice)
#define OFF_XN2     15467008u    // f32  xn2[64*512]  (overlays slice)

typedef __attribute__((ext_vector_type(4))) float v4f;
typedef __attribute__((ext_vector_type(4))) unsigned short u16x4;

__device__ __forceinline__ float b2f(unsigned short h) {
    union { unsigned int u; float f; } v; v.u = ((unsigned int)h) << 16; return v.f;
}
__device__ __forceinline__ unsigned short f2b(float f) {
    union { float f; unsigned int u; } v; v.f = f;
    unsigned int u = v.u;
    u += 0x7fffu + ((u >> 16) & 1u);
    return (unsigned short)(u >> 16);
}

__global__ void prep_k(const float* __restrict__ xin, unsigned short* __restrict__ x0) {
    __shared__ unsigned short tl[64][65];
    int t = threadIdx.x;
    int v0 = blockIdx.x * 64;
    #pragma unroll
    for (int i = 0; i < 16; i++) {
        int idx = t + i * 256;
        int b = idx >> 6, v = idx & 63;
        tl[v][b] = f2b(xin[(size_t)b * V_ + v0 + v]);
    }
    __syncthreads();
    #pragma unroll
    for (int i = 0; i < 16; i++) {
        int idx = t + i * 256;
        int v = idx >> 6, b = idx & 63;
        x0[(size_t)(v0 + v) * B_ + b] = tl[v][b];
    }
}

__global__ void count_k(const int* __restrict__ rows, int* __restrict__ cnt) {
    int e = blockIdx.x * 256 + threadIdx.x;
    if (e < E_) atomicAdd(&cnt[rows[e] & (V_ - 1)], 1);
}

__global__ void scan_k(int* __restrict__ cnt_cursor, int* __restrict__ row_start) {
    __shared__ int sums[256];
    int t = threadIdx.x;
    int loc[64];
    int s = 0;
    #pragma unroll
    for (int i = 0; i < 64; i++) { loc[i] = cnt_cursor[t * 64 + i]; s += loc[i]; }
    sums[t] = s;
    __syncthreads();
    for (int off = 1; off < 256; off <<= 1) {
        int v = (t >= off) ? sums[t - off] : 0;
        __syncthreads();
        sums[t] += v;
        __syncthreads();
    }
    int base = (t == 0) ? 0 : sums[t - 1];
    #pragma unroll
    for (int i = 0; i < 64; i++) {
        row_start[t * 64 + i] = base;
        cnt_cursor[t * 64 + i] = base;
        base += loc[i];
    }
    if (t == 255) row_start[V_] = base;
}

__global__ void scatter_k(const int* __restrict__ rows, const int* __restrict__ cols,
                          const float* __restrict__ vals,
                          int* __restrict__ cursor, unsigned short* __restrict__ scol,
                          unsigned short* __restrict__ sval) {
    int e = blockIdx.x * 256 + threadIdx.x;
    if (e < E_) {
        int r = rows[e] & (V_ - 1);
        int p = atomicAdd(&cursor[r], 1);
        scol[p] = (unsigned short)(cols[e] & (V_ - 1));
        sval[p] = f2b(vals[e]);
    }
}

__global__ void spmm_k(const int* __restrict__ row_start, const unsigned short* __restrict__ scol,
                       const unsigned short* __restrict__ sval,
                       const unsigned short* __restrict__ x,
                       const unsigned short* __restrict__ xprev, unsigned short* __restrict__ y,
                       int mode) {
    int row  = blockIdx.x * 4 + (threadIdx.x >> 6);
    int lane = threadIdx.x & 63;
    int s = row_start[row], e = row_start[row + 1];
    float acc = 0.f;
    for (int i = s; i < e; i++)
        acc += b2f(sval[i]) * b2f(x[(size_t)scol[i] * B_ + lane]);
    size_t o = (size_t)row * B_ + lane;
    float r = mode ? (2.f * acc - b2f(xprev[o])) : acc;
    y[o] = f2b(r);
}

__global__ void cheby_slice_k(const unsigned short* __restrict__ xs, const float* __restrict__ w,
                              const float* __restrict__ bias, unsigned short* __restrict__ slice,
                              int g) {
    __shared__ float tile[KCH * 512];
    __shared__ float wf[FCH * KCH];
    __shared__ float bf[FCH];
    int t = threadIdx.x;
    int vpl = blockIdx.x;
    int vp = g * 256 + vpl;
    for (int i = t; i < KCH * 512; i += 256) {
        int k = i >> 9, rem = i & 511;
        tile[i] = b2f(xs[(size_t)k * V_ * B_ + (size_t)vp * 512 + rem]);
    }
    if (t < FCH * KCH) wf[t] = w[t];
    if (t < FCH) bf[t] = bias[t];
    __syncthreads();
    int f = t & 31, b0 = t >> 5;
    float wr[KCH];
    #pragma unroll
    for (int k = 0; k < KCH; k++) wr[k] = wf[f * KCH + k];
    float bb = bf[f];
    #pragma unroll
    for (int bi = 0; bi < 8; bi++) {
        int b = b0 * 8 + bi;
        float m = -1e30f;
        #pragma unroll
        for (int j = 0; j < 8; j++) {
            float s = bb;
            #pragma unroll
            for (int k = 0; k < KCH; k++) s += tile[k * 512 + j * 64 + b] * wr[k];
            m = fmaxf(m, s);
        }
        slice[(size_t)b * 8192 + vpl * FCH + f] = f2b(fmaxf(m, 0.f));
    }
}

// ---- LDS-tiled VALU GEMM: C[64,N] = A[64,K] @ W[N,K]^T ----
// Block tile: 64m x 64n ; thread tile 4x4 ; A and W staged to LDS [k][row]+pad.
// grid.x = N/64, grid.y = K-split ; klen = K/grid.y (multiple of KT2).
// direct=1: Co = acc + bias (relu?).
// direct=0: Cp[y][64][N] = acc (accum=0) or += acc (accum=1). Each (y,cell) is
// owned by exactly one block per launch; accumulation only across sequential
// launches -> no race, no atomics, no zero-init memset needed.
__global__ void gemm2_k(const void* __restrict__ Av, int a32, int lda, int ka0,
                        const float* __restrict__ W, int ldw, int kw0,
                        int klen, int N, const float* __restrict__ bias,
                        int relu, int direct, int accum,
                        float* __restrict__ Cp, float* __restrict__ Co) {
    __shared__ float As[KT2][68];
    __shared__ float Ws[KT2][68];
    const unsigned short* Au = (const unsigned short*)Av;
    const float* Af = (const float*)Av;
    int t = threadIdx.x;
    int nb = blockIdx.x * 64;
    int ka = ka0 + blockIdx.y * klen;
    int kw = kw0 + blockIdx.y * klen;
    int kq = t & 15;            // k-quad for staging
    int r0 = t >> 4;            // staging row base (16 rows/pass)
    int tm = (t & 15) << 2;     // compute m0
    int tn = (t >> 4) << 2;     // compute n0
    float acc[4][4] = {{0.f, 0.f, 0.f, 0.f}, {0.f, 0.f, 0.f, 0.f},
                       {0.f, 0.f, 0.f, 0.f}, {0.f, 0.f, 0.f, 0.f}};
    for (int kt = 0; kt < klen; kt += KT2) {
        __syncthreads();
        #pragma unroll
        for (int p = 0; p < 4; p++) {
            int row = r0 + p * 16;
            int kk = kq << 2;
            float a0, a1, a2, a3;
            if (a32) {
                v4f v = *(const v4f*)(Af + (size_t)row * lda + ka + kt + kk);
                a0 = v[0]; a1 = v[1]; a2 = v[2]; a3 = v[3];
            } else {
                u16x4 h = *(const u16x4*)(Au + (size_t)row * lda + ka + kt + kk);
                a0 = b2f(h[0]); a1 = b2f(h[1]); a2 = b2f(h[2]); a3 = b2f(h[3]);
            }
            As[kk + 0][row] = a0; As[kk + 1][row] = a1;
            As[kk + 2][row] = a2; As[kk + 3][row] = a3;
            v4f w = *(const v4f*)(W + (size_t)(nb + row) * ldw + kw + kt + kk);
            Ws[kk + 0][row] = w[0]; Ws[kk + 1][row] = w[1];
            Ws[kk + 2][row] = w[2]; Ws[kk + 3][row] = w[3];
        }
        __syncthreads();
        #pragma unroll 8
        for (int k = 0; k < KT2; k++) {
            v4f a = *(const v4f*)&As[k][tm];
            v4f w = *(const v4f*)&Ws[k][tn];
            #pragma unroll
            for (int i = 0; i < 4; i++)
                #pragma unroll
                for (int j = 0; j < 4; j++)
                    acc[i][j] += a[i] * w[j];
        }
    }
    if (direct) {
        #pragma unroll
        for (int i = 0; i < 4; i++) {
            int m = tm + i;
            v4f v;
            #pragma unroll
            for (int j = 0; j < 4; j++) {
                float x = acc[i][j] + bias[nb + tn + j];
                v[j] = relu ? fmaxf(x, 0.f) : x;
            }
            *(v4f*)(Co + (size_t)m * N + nb + tn) = v;
        }
    } else {
        float* base = Cp + (size_t)blockIdx.y * 64 * N;
        #pragma unroll
        for (int i = 0; i < 4; i++) {
            int m = tm + i;
            float* p = base + (size_t)m * N + nb + tn;
            v4f v;
            if (accum) {
                v4f old = *(const v4f*)p;
                #pragma unroll
                for (int j = 0; j < 4; j++) v[j] = old[j] + acc[i][j];
            } else {
                #pragma unroll
                for (int j = 0; j < 4; j++) v[j] = acc[i][j];
            }
            *(v4f*)p = v;
        }
    }
}

// sum Y partial slices Cp[y][len], add bias, optional relu
__global__ void finish2_k(const float* __restrict__ Cp, int Y, int len,
                          const float* __restrict__ bias, int nmask, int relu,
                          float* __restrict__ o) {
    int i = blockIdx.x * 256 + threadIdx.x;
    float s = bias[i & nmask];
    for (int y = 0; y < Y; y++) s += Cp[(size_t)y * len + i];
    if (relu) s = fmaxf(s, 0.f);
    o[i] = s;
}

__global__ void sum2_k(const float* __restrict__ xh, const float* __restrict__ xn,
                       const float* __restrict__ w, const float* __restrict__ bias,
                       float* __restrict__ out) {
    int b = blockIdx.x;
    int lane = threadIdx.x;
    float xc[16];
    #pragma unroll
    for (int j = 0; j < 8; j++) xc[j] = xh[b * FC1F + j * 64 + lane];
    #pragma unroll
    for (int j = 0; j < 8; j++) xc[8 + j] = xn[b * NN2F + j * 64 + lane];
    float logits[OUTC];
    #pragma unroll
    for (int o = 0; o < OUTC; o++) {
        float s = 0.f;
        #pragma unroll
        for (int j = 0; j < 16; j++) s += xc[j] * w[o * 1024 + j * 64 + lane];
        #pragma unroll
        for (int off = 32; off; off >>= 1) s += __shfl_xor(s, off);
        logits[o] = s + bias[o];
    }
    float mx = logits[0];
    #pragma unroll
    for (int o = 1; o < OUTC; o++) mx = fmaxf(mx, logits[o]);
    float lse = 0.f;
    #pragma unroll
    for (int o = 0; o < OUTC; o++) lse += expf(logits[o] - mx);
    float lg = logf(lse) + mx;
    if (lane < OUTC) out[b * OUTC + lane] = logits[lane] - lg;
}

extern "C" void kernel_launch(void* const* d_in, const int* in_sizes, int n_in,
                              void* d_out, int out_size, void* d_ws, size_t ws_size,
                              hipStream_t stream) {
    const float* x_in   = (const float*)d_in[0];
    const float* L_vals = (const float*)d_in[1];
    const float* cl1_w  = (const float*)d_in[2];
    const float* cl1_b  = (const float*)d_in[3];
    const float* fc1_w  = (const float*)d_in[4];
    const float* fc1_b  = (const float*)d_in[5];
    const float* fc2_w  = (const float*)d_in[6];
    const float* fc2_b  = (const float*)d_in[7];
    const float* fc3_w  = (const float*)d_in[8];
    const float* fc3_b  = (const float*)d_in[9];
    const float* nn1_w  = (const float*)d_in[10];
    const float* nn1_b  = (const float*)d_in[11];
    const float* nn2_w  = (const float*)d_in[12];
    const float* nn2_b  = (const float*)d_in[13];
    const float* sum2_w = (const float*)d_in[14];
    const float* sum2_b = (const float*)d_in[15];
    const int* L_rows = (const int*)d_in[16];
    const int* L_cols = (const int*)d_in[17];
    float* out = (float*)d_out;
    char* ws = (char*)d_ws;

    unsigned short* xs     = (unsigned short*)(ws + OFF_XS);
    unsigned short* scol   = (unsigned short*)(ws + OFF_SCOL);
    unsigned short* sval   = (unsigned short*)(ws + OFF_SVAL);
    int*            rstart = (int*)(ws + OFF_RSTART);
    int*            cnt    = (int*)(ws + OFF_CNT);
    unsigned short* slice  = (unsigned short*)(ws + OFF_SLICE);
    float*          xd     = (float*)(ws + OFF_XD);
    float*          xn1    = (float*)(ws + OFF_XN1);
    float*          xn2    = (float*)(ws + OFF_XN2);
    float*          cp_a   = (float*)(ws + OFF_SCOL);   // 2 MB (fc1: 16 slices, fc2: 8 slices)
    float*          cp_b   = (float*)(ws + OFF_XS);     // up to 8 MB (nn1: 32 slices, nn2: 16)

    float* out_decode = out;                          // f32 [64,16384]
    float* out_hidden = out + (size_t)B_ * V_;        // f32 [64,512]
    float* out_logp   = out_hidden + B_ * FC1F;       // f32 [64,10]

    prep_k<<<V_ / 64, 256, 0, stream>>>(x_in, xs);

    hipMemsetAsync(cnt, 0, V_ * sizeof(int), stream);
    count_k<<<E_ / 256, 256, 0, stream>>>(L_rows, cnt);
    scan_k<<<1, 256, 0, stream>>>(cnt, rstart);
    scatter_k<<<E_ / 256, 256, 0, stream>>>(L_rows, L_cols, L_vals, cnt, scol, sval);

    size_t VB = (size_t)V_ * B_;
    spmm_k<<<V_ / 4, 256, 0, stream>>>(rstart, scol, sval, xs, nullptr, xs + VB, 0);
    for (int k = 2; k < KCH; k++)
        spmm_k<<<V_ / 4, 256, 0, stream>>>(rstart, scol, sval,
                                           xs + (k - 1) * VB, xs + (k - 2) * VB, xs + k * VB, 1);

    // fc1: 8 x (cheby slice -> K-split gemm accumulating into Cp[16]), then finish.
    // scol/sval (2 MB) are dead after spmm -> Cp for fc1. g=0 stores, g>0 accumulate.
    for (int g = 0; g < 8; g++) {
        cheby_slice_k<<<256, 256, 0, stream>>>(xs, cl1_w, cl1_b, slice, g);
        gemm2_k<<<dim3(FC1F / 64, 16), 256, 0, stream>>>(slice, 0, 8192, 0,
                                                         fc1_w, FIN1, g * 8192,
                                                         512, FC1F, nullptr, 0, 0, g ? 1 : 0,
                                                         cp_a, nullptr);
    }
    finish2_k<<<B_ * FC1F / 256, 256, 0, stream>>>(cp_a, 16, B_ * FC1F, fc1_b, FC1F - 1, 1, out_hidden);

    // fc2 (K=512, y=8, klen=64) -> xd
    gemm2_k<<<dim3(FC2F / 64, 8), 256, 0, stream>>>(out_hidden, 1, FC1F, 0,
                                                    fc2_w, FC1F, 0,
                                                    64, FC2F, nullptr, 0, 0, 0, cp_a, nullptr);
    finish2_k<<<B_ * FC2F / 256, 256, 0, stream>>>(cp_a, 8, B_ * FC2F, fc2_b, FC2F - 1, 1, xd);

    // fc3 (K=512, direct, no relu) -> out_decode : 256 blocks
    gemm2_k<<<dim3(V_ / 64, 1), 256, 0, stream>>>(xd, 1, FC2F, 0,
                                                  fc3_w, FC2F, 0,
                                                  FC2F, V_, fc3_b, 0, 1, 0, nullptr, out_decode);

    // nn1 (K=16384, y=32, klen=512) -> xn1 ; xs dead now -> Cp (8 MB)
    gemm2_k<<<dim3(NN1F / 64, 32), 256, 0, stream>>>(x_in, 1, V_, 0,
                                                     nn1_w, V_, 0,
                                                     512, NN1F, nullptr, 0, 0, 0, cp_b, nullptr);
    finish2_k<<<B_ * NN1F / 256, 256, 0, stream>>>(cp_b, 32, B_ * NN1F, nn1_b, NN1F - 1, 1, xn1);

    // nn2 (K=1024, y=16, klen=64) -> xn2
    gemm2_k<<<dim3(NN2F / 64, 16), 256, 0, stream>>>(xn1, 1, NN1F, 0,
                                                     nn2_w, NN1F, 0,
                                                     64, NN2F, nullptr, 0, 0, 0, cp_b, nullptr);
    finish2_k<<<B_ * NN2F / 256, 256, 0, stream>>>(cp_b, 16, B_ * NN2F, nn2_b, NN2F - 1, 1, xn2);

    sum2_k<<<B_, 64, 0, stream>>>(out_hidden, xn2, sum2_w, sum2_b, out_logp);
}

// Round 4
// 870.627 us; speedup vs baseline: 9.7859x; 1.2523x over previous
//
#include <hip/hip_runtime.h>

// Fixed shapes
#define B_    64
#define V_    16384
#define E_    524288
#define KCH   6
#define FCH   32
#define FIN1  65536
#define FC1F  512
#define FC2F  512
#define NN1F  1024
#define NN2F  512
#define OUTC  10
#define KT2   64

// workspace layout (bytes), total 16,122,368
#define OFF_XS      0u           // bf16 xs[6][V][B]      12,582,912 ; dead after last cheby_slice -> Cp for nn1/nn2
#define OFF_SCOL    12582912u    // u16  scol[E]           1,048,576 ; scol+sval dead after spmm -> Cp for fc1/fc2 (2 MB)
#define OFF_SVAL    13631488u    // bf16 sval[E]           1,048,576
#define OFF_RSTART  14680064u    // i32  rstart[V+1]          66,048
#define OFF_CNT     14746112u    // i32  cnt/cursor[V]        65,536
#define OFF_CF      14811648u    // f32  Cf[64*1024]         262,144 (unused now)
#define OFF_SLICE   15073792u    // bf16 slice[64*8192]    1,048,576 (dead after fc1)
#define OFF_XD      15073792u    // f32  xd[64*512]   (overlays slice)
#define OFF_XN1     15204864u    // f32  xn1[64*1024] (overlays slice)
#define OFF_XN2     15467008u    // f32  xn2[64*512]  (overlays slice)

typedef __attribute__((ext_vector_type(4))) float v4f;
typedef __attribute__((ext_vector_type(2))) float v2f;
typedef __attribute__((ext_vector_type(4))) unsigned short u16x4;

__device__ __forceinline__ float b2f(unsigned short h) {
    union { unsigned int u; float f; } v; v.u = ((unsigned int)h) << 16; return v.f;
}
__device__ __forceinline__ unsigned short f2b(float f) {
    union { float f; unsigned int u; } v; v.f = f;
    unsigned int u = v.u;
    u += 0x7fffu + ((u >> 16) & 1u);
    return (unsigned short)(u >> 16);
}

__global__ void prep_k(const float* __restrict__ xin, unsigned short* __restrict__ x0) {
    __shared__ unsigned short tl[64][65];
    int t = threadIdx.x;
    int v0 = blockIdx.x * 64;
    #pragma unroll
    for (int i = 0; i < 16; i++) {
        int idx = t + i * 256;
        int b = idx >> 6, v = idx & 63;
        tl[v][b] = f2b(xin[(size_t)b * V_ + v0 + v]);
    }
    __syncthreads();
    #pragma unroll
    for (int i = 0; i < 16; i++) {
        int idx = t + i * 256;
        int v = idx >> 6, b = idx & 63;
        x0[(size_t)(v0 + v) * B_ + b] = tl[v][b];
    }
}

__global__ void count_k(const int* __restrict__ rows, int* __restrict__ cnt) {
    int e = blockIdx.x * 256 + threadIdx.x;
    if (e < E_) atomicAdd(&cnt[rows[e] & (V_ - 1)], 1);
}

__global__ void scan_k(int* __restrict__ cnt_cursor, int* __restrict__ row_start) {
    __shared__ int sums[256];
    int t = threadIdx.x;
    int loc[64];
    int s = 0;
    #pragma unroll
    for (int i = 0; i < 64; i++) { loc[i] = cnt_cursor[t * 64 + i]; s += loc[i]; }
    sums[t] = s;
    __syncthreads();
    for (int off = 1; off < 256; off <<= 1) {
        int v = (t >= off) ? sums[t - off] : 0;
        __syncthreads();
        sums[t] += v;
        __syncthreads();
    }
    int base = (t == 0) ? 0 : sums[t - 1];
    #pragma unroll
    for (int i = 0; i < 64; i++) {
        row_start[t * 64 + i] = base;
        cnt_cursor[t * 64 + i] = base;
        base += loc[i];
    }
    if (t == 255) row_start[V_] = base;
}

__global__ void scatter_k(const int* __restrict__ rows, const int* __restrict__ cols,
                          const float* __restrict__ vals,
                          int* __restrict__ cursor, unsigned short* __restrict__ scol,
                          unsigned short* __restrict__ sval) {
    int e = blockIdx.x * 256 + threadIdx.x;
    if (e < E_) {
        int r = rows[e] & (V_ - 1);
        int p = atomicAdd(&cursor[r], 1);
        scol[p] = (unsigned short)(cols[e] & (V_ - 1));
        sval[p] = f2b(vals[e]);
    }
}

// one wave per row; 4-way unrolled gather for ILP (4 loads in flight)
__global__ void spmm_k(const int* __restrict__ row_start, const unsigned short* __restrict__ scol,
                       const unsigned short* __restrict__ sval,
                       const unsigned short* __restrict__ x,
                       const unsigned short* __restrict__ xprev, unsigned short* __restrict__ y,
                       int mode) {
    int row  = blockIdx.x * 4 + (threadIdx.x >> 6);
    int lane = threadIdx.x & 63;
    int s = row_start[row], e = row_start[row + 1];
    float a0 = 0.f, a1 = 0.f, a2 = 0.f, a3 = 0.f;
    int i = s;
    for (; i + 4 <= e; i += 4) {
        int c0 = scol[i], c1 = scol[i + 1], c2 = scol[i + 2], c3 = scol[i + 3];
        float v0 = b2f(sval[i]), v1 = b2f(sval[i + 1]);
        float v2 = b2f(sval[i + 2]), v3 = b2f(sval[i + 3]);
        a0 += v0 * b2f(x[(size_t)c0 * B_ + lane]);
        a1 += v1 * b2f(x[(size_t)c1 * B_ + lane]);
        a2 += v2 * b2f(x[(size_t)c2 * B_ + lane]);
        a3 += v3 * b2f(x[(size_t)c3 * B_ + lane]);
    }
    for (; i < e; i++)
        a0 += b2f(sval[i]) * b2f(x[(size_t)scol[i] * B_ + lane]);
    float acc = (a0 + a1) + (a2 + a3);
    size_t o = (size_t)row * B_ + lane;
    float r = mode ? (2.f * acc - b2f(xprev[o])) : acc;
    y[o] = f2b(r);
}

__global__ void cheby_slice_k(const unsigned short* __restrict__ xs, const float* __restrict__ w,
                              const float* __restrict__ bias, unsigned short* __restrict__ slice,
                              int g) {
    __shared__ float tile[KCH * 512];
    __shared__ float wf[FCH * KCH];
    __shared__ float bf[FCH];
    int t = threadIdx.x;
    int vpl = blockIdx.x;
    int vp = g * 256 + vpl;
    for (int i = t; i < KCH * 512; i += 256) {
        int k = i >> 9, rem = i & 511;
        tile[i] = b2f(xs[(size_t)k * V_ * B_ + (size_t)vp * 512 + rem]);
    }
    if (t < FCH * KCH) wf[t] = w[t];
    if (t < FCH) bf[t] = bias[t];
    __syncthreads();
    int f = t & 31, b0 = t >> 5;
    float wr[KCH];
    #pragma unroll
    for (int k = 0; k < KCH; k++) wr[k] = wf[f * KCH + k];
    float bb = bf[f];
    #pragma unroll
    for (int bi = 0; bi < 8; bi++) {
        int b = b0 * 8 + bi;
        float m = -1e30f;
        #pragma unroll
        for (int j = 0; j < 8; j++) {
            float s = bb;
            #pragma unroll
            for (int k = 0; k < KCH; k++) s += tile[k * 512 + j * 64 + b] * wr[k];
            m = fmaxf(m, s);
        }
        slice[(size_t)b * 8192 + vpl * FCH + f] = f2b(fmaxf(m, 0.f));
    }
}

// ---- LDS-tiled VALU GEMM: C[64,N] = A[64,K] @ W[N,K]^T ----
// Block tile: 64m x 32n ; thread tile 2x4 ; A and W staged to LDS [k][row]+pad.
// grid.x = N/32, grid.y = K-split ; klen = K/grid.y (multiple of KT2).
// direct=1: Co = acc + bias (relu?).
// direct=0: Cp[y][64][N] = acc (accum=0) or += acc (accum=1). Each (y,cell) is
// owned by exactly one block per launch; accumulation only across sequential
// launches -> no race, no atomics.
__global__ void gemm3_k(const void* __restrict__ Av, int a32, int lda, int ka0,
                        const float* __restrict__ W, int ldw, int kw0,
                        int klen, int N, const float* __restrict__ bias,
                        int relu, int direct, int accum,
                        float* __restrict__ Cp, float* __restrict__ Co) {
    __shared__ float As[KT2][68];
    __shared__ float Ws[KT2][36];
    const unsigned short* Au = (const unsigned short*)Av;
    const float* Af = (const float*)Av;
    int t = threadIdx.x;
    int nb = blockIdx.x * 32;
    int ka = ka0 + blockIdx.y * klen;
    int kw = kw0 + blockIdx.y * klen;
    int kq = t & 15;            // k-quad for staging
    int r0 = t >> 4;            // staging row base (16 rows/pass)
    int tm = (t & 31) << 1;     // compute m0 (2 rows)
    int tn = (t >> 5) << 2;     // compute n0 (4 cols)
    float acc[2][4] = {{0.f, 0.f, 0.f, 0.f}, {0.f, 0.f, 0.f, 0.f}};
    for (int kt = 0; kt < klen; kt += KT2) {
        __syncthreads();
        int kk = kq << 2;
        #pragma unroll
        for (int p = 0; p < 4; p++) {
            int row = r0 + p * 16;
            float a0, a1, a2, a3;
            if (a32) {
                v4f v = *(const v4f*)(Af + (size_t)row * lda + ka + kt + kk);
                a0 = v[0]; a1 = v[1]; a2 = v[2]; a3 = v[3];
            } else {
                u16x4 h = *(const u16x4*)(Au + (size_t)row * lda + ka + kt + kk);
                a0 = b2f(h[0]); a1 = b2f(h[1]); a2 = b2f(h[2]); a3 = b2f(h[3]);
            }
            As[kk + 0][row] = a0; As[kk + 1][row] = a1;
            As[kk + 2][row] = a2; As[kk + 3][row] = a3;
        }
        #pragma unroll
        for (int p = 0; p < 2; p++) {
            int row = r0 + p * 16;
            v4f w = *(const v4f*)(W + (size_t)(nb + row) * ldw + kw + kt + kk);
            Ws[kk + 0][row] = w[0]; Ws[kk + 1][row] = w[1];
            Ws[kk + 2][row] = w[2]; Ws[kk + 3][row] = w[3];
        }
        __syncthreads();
        #pragma unroll 8
        for (int k = 0; k < KT2; k++) {
            v2f a = *(const v2f*)&As[k][tm];
            v4f w = *(const v4f*)&Ws[k][tn];
            #pragma unroll
            for (int i = 0; i < 2; i++)
                #pragma unroll
                for (int j = 0; j < 4; j++)
                    acc[i][j] += a[i] * w[j];
        }
    }
    if (direct) {
        #pragma unroll
        for (int i = 0; i < 2; i++) {
            int m = tm + i;
            v4f v;
            #pragma unroll
            for (int j = 0; j < 4; j++) {
                float x = acc[i][j] + bias[nb + tn + j];
                v[j] = relu ? fmaxf(x, 0.f) : x;
            }
            *(v4f*)(Co + (size_t)m * N + nb + tn) = v;
        }
    } else {
        float* base = Cp + (size_t)blockIdx.y * 64 * N;
        #pragma unroll
        for (int i = 0; i < 2; i++) {
            int m = tm + i;
            float* p = base + (size_t)m * N + nb + tn;
            v4f v;
            if (accum) {
                v4f old = *(const v4f*)p;
                #pragma unroll
                for (int j = 0; j < 4; j++) v[j] = old[j] + acc[i][j];
            } else {
                #pragma unroll
                for (int j = 0; j < 4; j++) v[j] = acc[i][j];
            }
            *(v4f*)p = v;
        }
    }
}

// sum Y partial slices Cp[y][len], add bias, optional relu
__global__ void finish2_k(const float* __restrict__ Cp, int Y, int len,
                          const float* __restrict__ bias, int nmask, int relu,
                          float* __restrict__ o) {
    int i = blockIdx.x * 256 + threadIdx.x;
    float s = bias[i & nmask];
    for (int y = 0; y < Y; y++) s += Cp[(size_t)y * len + i];
    if (relu) s = fmaxf(s, 0.f);
    o[i] = s;
}

__global__ void sum2_k(const float* __restrict__ xh, const float* __restrict__ xn,
                       const float* __restrict__ w, const float* __restrict__ bias,
                       float* __restrict__ out) {
    int b = blockIdx.x;
    int lane = threadIdx.x;
    float xc[16];
    #pragma unroll
    for (int j = 0; j < 8; j++) xc[j] = xh[b * FC1F + j * 64 + lane];
    #pragma unroll
    for (int j = 0; j < 8; j++) xc[8 + j] = xn[b * NN2F + j * 64 + lane];
    float logits[OUTC];
    #pragma unroll
    for (int o = 0; o < OUTC; o++) {
        float s = 0.f;
        #pragma unroll
        for (int j = 0; j < 16; j++) s += xc[j] * w[o * 1024 + j * 64 + lane];
        #pragma unroll
        for (int off = 32; off; off >>= 1) s += __shfl_xor(s, off);
        logits[o] = s + bias[o];
    }
    float mx = logits[0];
    #pragma unroll
    for (int o = 1; o < OUTC; o++) mx = fmaxf(mx, logits[o]);
    float lse = 0.f;
    #pragma unroll
    for (int o = 0; o < OUTC; o++) lse += expf(logits[o] - mx);
    float lg = logf(lse) + mx;
    if (lane < OUTC) out[b * OUTC + lane] = logits[lane] - lg;
}

extern "C" void kernel_launch(void* const* d_in, const int* in_sizes, int n_in,
                              void* d_out, int out_size, void* d_ws, size_t ws_size,
                              hipStream_t stream) {
    const float* x_in   = (const float*)d_in[0];
    const float* L_vals = (const float*)d_in[1];
    const float* cl1_w  = (const float*)d_in[2];
    const float* cl1_b  = (const float*)d_in[3];
    const float* fc1_w  = (const float*)d_in[4];
    const float* fc1_b  = (const float*)d_in[5];
    const float* fc2_w  = (const float*)d_in[6];
    const float* fc2_b  = (const float*)d_in[7];
    const float* fc3_w  = (const float*)d_in[8];
    const float* fc3_b  = (const float*)d_in[9];
    const float* nn1_w  = (const float*)d_in[10];
    const float* nn1_b  = (const float*)d_in[11];
    const float* nn2_w  = (const float*)d_in[12];
    const float* nn2_b  = (const float*)d_in[13];
    const float* sum2_w = (const float*)d_in[14];
    const float* sum2_b = (const float*)d_in[15];
    const int* L_rows = (const int*)d_in[16];
    const int* L_cols = (const int*)d_in[17];
    float* out = (float*)d_out;
    char* ws = (char*)d_ws;

    unsigned short* xs     = (unsigned short*)(ws + OFF_XS);
    unsigned short* scol   = (unsigned short*)(ws + OFF_SCOL);
    unsigned short* sval   = (unsigned short*)(ws + OFF_SVAL);
    int*            rstart = (int*)(ws + OFF_RSTART);
    int*            cnt    = (int*)(ws + OFF_CNT);
    unsigned short* slice  = (unsigned short*)(ws + OFF_SLICE);
    float*          xd     = (float*)(ws + OFF_XD);
    float*          xn1    = (float*)(ws + OFF_XN1);
    float*          xn2    = (float*)(ws + OFF_XN2);
    float*          cp_a   = (float*)(ws + OFF_SCOL);   // 2 MB (fc1: 16 slices, fc2: 8 slices)
    float*          cp_b   = (float*)(ws + OFF_XS);     // up to 8 MB (nn1: 32 slices, nn2: 16)

    float* out_decode = out;                          // f32 [64,16384]
    float* out_hidden = out + (size_t)B_ * V_;        // f32 [64,512]
    float* out_logp   = out_hidden + B_ * FC1F;       // f32 [64,10]

    prep_k<<<V_ / 64, 256, 0, stream>>>(x_in, xs);

    hipMemsetAsync(cnt, 0, V_ * sizeof(int), stream);
    count_k<<<E_ / 256, 256, 0, stream>>>(L_rows, cnt);
    scan_k<<<1, 256, 0, stream>>>(cnt, rstart);
    scatter_k<<<E_ / 256, 256, 0, stream>>>(L_rows, L_cols, L_vals, cnt, scol, sval);

    size_t VB = (size_t)V_ * B_;
    spmm_k<<<V_ / 4, 256, 0, stream>>>(rstart, scol, sval, xs, nullptr, xs + VB, 0);
    for (int k = 2; k < KCH; k++)
        spmm_k<<<V_ / 4, 256, 0, stream>>>(rstart, scol, sval,
                                           xs + (k - 1) * VB, xs + (k - 2) * VB, xs + k * VB, 1);

    // fc1: 8 x (cheby slice -> K-split gemm accumulating into Cp[16]), then finish.
    // scol/sval (2 MB) are dead after spmm -> Cp for fc1. g=0 stores, g>0 accumulate.
    for (int g = 0; g < 8; g++) {
        cheby_slice_k<<<256, 256, 0, stream>>>(xs, cl1_w, cl1_b, slice, g);
        gemm3_k<<<dim3(FC1F / 32, 16), 256, 0, stream>>>(slice, 0, 8192, 0,
                                                         fc1_w, FIN1, g * 8192,
                                                         512, FC1F, nullptr, 0, 0, g ? 1 : 0,
                                                         cp_a, nullptr);
    }
    finish2_k<<<B_ * FC1F / 256, 256, 0, stream>>>(cp_a, 16, B_ * FC1F, fc1_b, FC1F - 1, 1, out_hidden);

    // fc2 (K=512, y=8, klen=64) -> xd
    gemm3_k<<<dim3(FC2F / 32, 8), 256, 0, stream>>>(out_hidden, 1, FC1F, 0,
                                                    fc2_w, FC1F, 0,
                                                    64, FC2F, nullptr, 0, 0, 0, cp_a, nullptr);
    finish2_k<<<B_ * FC2F / 256, 256, 0, stream>>>(cp_a, 8, B_ * FC2F, fc2_b, FC2F - 1, 1, xd);

    // fc3 (K=512, direct, no relu) -> out_decode : 512 blocks
    gemm3_k<<<dim3(V_ / 32, 1), 256, 0, stream>>>(xd, 1, FC2F, 0,
                                                  fc3_w, FC2F, 0,
                                                  FC2F, V_, fc3_b, 0, 1, 0, nullptr, out_decode);

    // nn1 (K=16384, y=32, klen=512) -> xn1 ; xs dead now -> Cp (8 MB)
    gemm3_k<<<dim3(NN1F / 32, 32), 256, 0, stream>>>(x_in, 1, V_, 0,
                                                     nn1_w, V_, 0,
                                                     512, NN1F, nullptr, 0, 0, 0, cp_b, nullptr);
    finish2_k<<<B_ * NN1F / 256, 256, 0, stream>>>(cp_b, 32, B_ * NN1F, nn1_b, NN1F - 1, 1, xn1);

    // nn2 (K=1024, y=16, klen=64) -> xn2
    gemm3_k<<<dim3(NN2F / 32, 16), 256, 0, stream>>>(xn1, 1, NN1F, 0,
                                                     nn2_w, NN1F, 0,
                                                     64, NN2F, nullptr, 0, 0, 0, cp_b, nullptr);
    finish2_k<<<B_ * NN2F / 256, 256, 0, stream>>>(cp_b, 16, B_ * NN2F, nn2_b, NN2F - 1, 1, xn2);

    sum2_k<<<B_, 64, 0, stream>>>(out_hidden, xn2, sum2_w, sum2_b, out_logp);
}